// Round 2
// baseline (1655.524 us; speedup 1.0000x reference)
//
#include <hip/hip_runtime.h>
#include <hip/hip_bf16.h>

#define DEV __device__ __forceinline__

typedef unsigned short u16;
typedef unsigned int u32;
typedef float f32x4 __attribute__((ext_vector_type(4)));
typedef short s16x8 __attribute__((ext_vector_type(8)));

static constexpr int Bb = 4, Ll = 2048, DM = 1024, DI = 2048, NH = 32;
static constexpr int CD = 2304;       // conv dim
static constexpr int NP = 4384;       // d_in_proj
static constexpr int NP_PAD = 4480;   // 35*128
static constexpr int BL = Bb * Ll;    // 8192

DEV float u2f(u16 s) { return __uint_as_float(((u32)s) << 16); }
DEV u16 f2bu(float f) {
  __hip_bfloat16 h = __float2bfloat16(f);
  u16 s; __builtin_memcpy(&s, &h, 2); return s;
}
DEV float blo(u32 u) { return __uint_as_float(u << 16); }
DEV float bhi(u32 u) { return __uint_as_float(u & 0xffff0000u); }

// ---------------- weight convert (+row pad) ----------------
__global__ __launch_bounds__(256) void cvt_pad(const float* __restrict__ src,
    u16* __restrict__ dst, int total, int cols, int realRows) {
  int i = blockIdx.x * 256 + threadIdx.x;
  if (i >= total) return;
  int r = i / cols;
  dst[i] = (r < realRows) ? f2bu(src[i]) : (u16)0;
}

// ---------------- LayerNorm -> bf16 ----------------
__global__ __launch_bounds__(256) void ln_kernel(const float* __restrict__ x,
    const float* __restrict__ w, const float* __restrict__ bia, u16* __restrict__ u) {
  int row = blockIdx.x, tid = threadIdx.x;
  const float4* xr = (const float4*)(x + (size_t)row * DM);
  float4 v = xr[tid];
  float s = v.x + v.y + v.z + v.w;
  float s2 = v.x*v.x + v.y*v.y + v.z*v.z + v.w*v.w;
  #pragma unroll
  for (int o = 32; o; o >>= 1) { s += __shfl_down(s, o); s2 += __shfl_down(s2, o); }
  __shared__ float rs[4], rs2[4];
  int wv = tid >> 6, ln = tid & 63;
  if (ln == 0) { rs[wv] = s; rs2[wv] = s2; }
  __syncthreads();
  s = rs[0] + rs[1] + rs[2] + rs[3];
  s2 = rs2[0] + rs2[1] + rs2[2] + rs2[3];
  float mu = s * (1.f / DM);
  float var = s2 * (1.f / DM) - mu * mu;
  float inv = rsqrtf(var + 1e-5f);
  float4 wv4 = ((const float4*)w)[tid], bv4 = ((const float4*)bia)[tid];
  ushort4 o;
  o.x = f2bu((v.x - mu) * inv * wv4.x + bv4.x);
  o.y = f2bu((v.y - mu) * inv * wv4.y + bv4.y);
  o.z = f2bu((v.z - mu) * inv * wv4.z + bv4.z);
  o.w = f2bu((v.w - mu) * inv * wv4.w + bv4.w);
  ((ushort4*)(u + (size_t)row * DM))[tid] = o;
}

// ---------------- bf16 MFMA GEMM:  C[m][n] = sum_k A[m][k]*B[n][k] ----------------
DEV void gl_lds16(const u16* g, u16* l) {
  __builtin_amdgcn_global_load_lds(
      (const __attribute__((address_space(1))) u32*)g,
      (__attribute__((address_space(3))) u32*)l, 16, 0, 0);
}

template<bool RESID>
__global__ __launch_bounds__(256) void gemm_nt(const u16* __restrict__ A,
    const u16* __restrict__ Bw, void* __restrict__ Cout,
    const float* __restrict__ resid, int N, int K) {
  __shared__ u16 sA[128 * 32];
  __shared__ u16 sB[128 * 32];
  int tid = threadIdx.x, wid = tid >> 6, lane = tid & 63;
  int m0 = blockIdx.x * 128, n0 = blockIdx.y * 128;
  int wm = (wid >> 1) * 64, wn = (wid & 1) * 64;
  f32x4 acc[4][4];
  #pragma unroll
  for (int i = 0; i < 4; i++)
    #pragma unroll
    for (int j = 0; j < 4; j++) acc[i][j] = (f32x4){0.f, 0.f, 0.f, 0.f};
  int rA = wid * 32 + (lane >> 2);
  int cA = (lane & 3) * 8;
  const u16* gA = A + (size_t)(m0 + rA) * K + cA;
  const u16* gB = Bw + (size_t)(n0 + rA) * K + cA;
  u16* lA0 = &sA[(wid * 2 + 0) * 512]; u16* lA1 = &sA[(wid * 2 + 1) * 512];
  u16* lB0 = &sB[(wid * 2 + 0) * 512]; u16* lB1 = &sB[(wid * 2 + 1) * 512];
  int fr = lane & 15, fk = (lane >> 4) * 8, fq = lane >> 4;
  for (int kk = 0; kk < K; kk += 32) {
    gl_lds16(gA + kk, lA0);
    gl_lds16(gA + (size_t)16 * K + kk, lA1);
    gl_lds16(gB + kk, lB0);
    gl_lds16(gB + (size_t)16 * K + kk, lB1);
    __syncthreads();
    s16x8 af[4], bfr[4];
    #pragma unroll
    for (int i = 0; i < 4; i++) af[i] = *(const s16x8*)&sA[(wm + i * 16 + fr) * 32 + fk];
    #pragma unroll
    for (int i = 0; i < 4; i++) bfr[i] = *(const s16x8*)&sB[(wn + i * 16 + fr) * 32 + fk];
    #pragma unroll
    for (int mi = 0; mi < 4; mi++)
      #pragma unroll
      for (int ni = 0; ni < 4; ni++)
        acc[mi][ni] = __builtin_amdgcn_mfma_f32_16x16x32_bf16(af[mi], bfr[ni], acc[mi][ni], 0, 0, 0);
    __syncthreads();
  }
  #pragma unroll
  for (int mi = 0; mi < 4; mi++) {
    #pragma unroll
    for (int ni = 0; ni < 4; ni++) {
      int col = n0 + wn + ni * 16 + fr;
      #pragma unroll
      for (int r = 0; r < 4; r++) {
        int row = m0 + wm + mi * 16 + fq * 4 + r;
        if (RESID) {
          float* of = (float*)Cout;
          of[(size_t)row * N + col] = acc[mi][ni][r] + resid[(size_t)row * N + col];
        } else {
          if (col < N) ((u16*)Cout)[(size_t)row * N + col] = f2bu(acc[mi][ni][r]);
        }
      }
    }
  }
}

// ---------------- depthwise causal conv(4) + SiLU ----------------
__global__ __launch_bounds__(256) void conv_silu(const u16* __restrict__ zx,
    const float* __restrict__ cw, const float* __restrict__ cb, u16* __restrict__ out) {
  int i = blockIdx.x * 256 + threadIdx.x;
  if (i >= BL * CD) return;
  int c = i % CD;
  int bl = i / CD;
  int l = bl % Ll;
  float acc = cb[c];
  #pragma unroll
  for (int k = 0; k < 4; ++k) {
    int ls = l - 3 + k;
    if (ls >= 0) acc += cw[c * 4 + k] * u2f(zx[(size_t)(bl - 3 + k) * NP + 2048 + c]);
  }
  float sg = 1.f / (1.f + __expf(-acc));
  out[i] = f2bu(acc * sg);
}

// ---------------- dt = softplus(raw + bias); dA = exp(dt * -exp(A_log)) ----------------
__global__ __launch_bounds__(256) void dt_da(const u16* __restrict__ zx,
    const float* __restrict__ dtb, const float* __restrict__ alog,
    float* __restrict__ dt, float* __restrict__ dA) {
  int i = blockIdx.x * 256 + threadIdx.x;
  if (i >= BL * NH) return;
  int h = i & 31, bl = i >> 5;
  float v = u2f(zx[(size_t)bl * NP + 4352 + h]) + dtb[h];
  float d = (v > 20.f) ? v : log1pf(__expf(v));
  dt[i] = d;
  dA[i] = __expf(-d * __expf(alog[h]));
}

// ---------------- selective scan: wg per (b,h), state in registers ----------------
__global__ __launch_bounds__(256) void scan_k(const u16* __restrict__ conv,
    const float* __restrict__ dtp, const float* __restrict__ dAp,
    const float* __restrict__ Dp, u16* __restrict__ y) {
  int b = blockIdx.x >> 5, h = blockIdx.x & 31;
  int tid = threadIdx.x, p = tid >> 2, q = tid & 3;
  float hreg[32];
  #pragma unroll
  for (int i = 0; i < 32; i++) hreg[i] = 0.f;
  float Dh = Dp[h];
  const u16* base = conv + (size_t)b * Ll * CD;
  const float* dtr = dtp + (size_t)b * Ll * NH + h;
  const float* dAr = dAp + (size_t)b * Ll * NH + h;
  u16* yr = y + (size_t)b * Ll * DI + h * 64 + p;
  for (int t = 0; t < Ll; ++t) {
    const u16* row = base + (size_t)t * CD;
    float dt = dtr[(size_t)t * NH];
    float dA = dAr[(size_t)t * NH];
    float xh = u2f(row[h * 64 + p]);
    float dtx = dt * xh;
    const uint4* Bv = (const uint4*)(row + 2048 + q * 32);
    const uint4* Cv = (const uint4*)(row + 2176 + q * 32);
    float acc = 0.f;
    #pragma unroll
    for (int j = 0; j < 4; j++) {
      uint4 bb = Bv[j], cc = Cv[j];
      float bv[8] = {blo(bb.x), bhi(bb.x), blo(bb.y), bhi(bb.y),
                     blo(bb.z), bhi(bb.z), blo(bb.w), bhi(bb.w)};
      float cv[8] = {blo(cc.x), bhi(cc.x), blo(cc.y), bhi(cc.y),
                     blo(cc.z), bhi(cc.z), blo(cc.w), bhi(cc.w)};
      #pragma unroll
      for (int e = 0; e < 8; e++) {
        float hn = dA * hreg[j * 8 + e] + dtx * bv[e];
        hreg[j * 8 + e] = hn;
        acc += hn * cv[e];
      }
    }
    acc += __shfl_xor(acc, 1);
    acc += __shfl_xor(acc, 2);
    if (q == 0) yr[(size_t)t * DI] = f2bu(acc + Dh * xh);
  }
}

// ---------------- g = y*silu(z), RMSNorm, *rms_w ----------------
__global__ __launch_bounds__(256) void gate_rms(const u16* __restrict__ y,
    const u16* __restrict__ zx, const float* __restrict__ rw, u16* __restrict__ g) {
  int bl = blockIdx.x, tid = threadIdx.x;
  uint4 yv = ((const uint4*)(y + (size_t)bl * DI))[tid];
  uint4 zv = ((const uint4*)(zx + (size_t)bl * NP))[tid];
  u32 ya[4] = {yv.x, yv.y, yv.z, yv.w};
  u32 za[4] = {zv.x, zv.y, zv.z, zv.w};
  float gv[8];
  float ss = 0.f;
  #pragma unroll
  for (int j = 0; j < 4; j++) {
    float y0 = blo(ya[j]), y1 = bhi(ya[j]);
    float z0 = blo(za[j]), z1 = bhi(za[j]);
    float s0 = z0 / (1.f + __expf(-z0));
    float s1 = z1 / (1.f + __expf(-z1));
    gv[j * 2] = y0 * s0; gv[j * 2 + 1] = y1 * s1;
    ss += gv[j * 2] * gv[j * 2] + gv[j * 2 + 1] * gv[j * 2 + 1];
  }
  #pragma unroll
  for (int o = 32; o; o >>= 1) ss += __shfl_down(ss, o);
  __shared__ float red[4];
  int wv = tid >> 6, ln = tid & 63;
  if (ln == 0) red[wv] = ss;
  __syncthreads();
  ss = red[0] + red[1] + red[2] + red[3];
  float scale = rsqrtf(ss * (1.f / DI) + 1e-5f);
  const float* rwp = rw + tid * 8;
  ushort4 o0, o1;
  o0.x = f2bu(gv[0] * scale * rwp[0]); o0.y = f2bu(gv[1] * scale * rwp[1]);
  o0.z = f2bu(gv[2] * scale * rwp[2]); o0.w = f2bu(gv[3] * scale * rwp[3]);
  o1.x = f2bu(gv[4] * scale * rwp[4]); o1.y = f2bu(gv[5] * scale * rwp[5]);
  o1.z = f2bu(gv[6] * scale * rwp[6]); o1.w = f2bu(gv[7] * scale * rwp[7]);
  ushort4* gp = (ushort4*)(g + (size_t)bl * DI + tid * 8);
  gp[0] = o0; gp[1] = o1;
}

extern "C" void kernel_launch(void* const* d_in, const int* in_sizes, int n_in,
                              void* d_out, int out_size, void* d_ws, size_t ws_size,
                              hipStream_t stream) {
  const float* x    = (const float*)d_in[0];
  const float* lnw  = (const float*)d_in[1];
  const float* lnb  = (const float*)d_in[2];
  const float* w1   = (const float*)d_in[3];
  const float* cw   = (const float*)d_in[4];
  const float* cb   = (const float*)d_in[5];
  const float* dtb  = (const float*)d_in[6];
  const float* alog = (const float*)d_in[7];
  const float* Dp   = (const float*)d_in[8];
  const float* rw   = (const float*)d_in[9];
  const float* w2   = (const float*)d_in[10];

  // workspace layout (bytes)
  char* ws = (char*)d_ws;
  u16*   W1b = (u16*)(ws + 0);          // 4480*1024*2  = 9,175,040
  u16*   W2b = (u16*)(ws + 9175040);    // 1024*2048*2  = 4,194,304
  u16*   ub  = (u16*)(ws + 13369344);   // 8192*1024*2  = 16,777,216
  u16*   zx  = (u16*)(ws + 30146560);   // 8192*4384*2  = 71,827,456
  u16*   cv  = (u16*)(ws + 101974016);  // 8192*2304*2  = 37,748,736
  float* dt  = (float*)(ws + 139722752);// 8192*32*4    = 1,048,576
  float* dA  = (float*)(ws + 140771328);// 1,048,576
  u16*   yb  = (u16*)(ws + 141819904);  // 8192*2048*2  = 33,554,432
  u16*   gb  = (u16*)(ws + 175374336);  // 33,554,432   -> end 208,928,768
  if (ws_size < 208928768u) return;     // insufficient scratch: fail loudly via validation

  float* out = (float*)d_out;

  cvt_pad<<<(NP_PAD * 1024) / 256, 256, 0, stream>>>(w1, W1b, NP_PAD * 1024, 1024, NP);
  cvt_pad<<<(1024 * 2048) / 256, 256, 0, stream>>>(w2, W2b, 1024 * 2048, 2048, 1024);
  ln_kernel<<<BL, 256, 0, stream>>>(x, lnw, lnb, ub);
  gemm_nt<false><<<dim3(64, 35), 256, 0, stream>>>(ub, W1b, zx, nullptr, NP, 1024);
  conv_silu<<<(BL * CD) / 256, 256, 0, stream>>>(zx, cw, cb, cv);
  dt_da<<<(BL * NH) / 256, 256, 0, stream>>>(zx, dtb, alog, dt, dA);
  scan_k<<<128, 256, 0, stream>>>(cv, dt, dA, Dp, yb);
  gate_rms<<<BL, 256, 0, stream>>>(yb, zx, rw, gb);
  gemm_nt<true><<<dim3(64, 8), 256, 0, stream>>>(gb, W2b, out, x, 1024, 2048);
}

// Round 4
// 402.227 us; speedup vs baseline: 4.1159x; 4.1159x over previous
//
#include <hip/hip_runtime.h>
#include <hip/hip_bf16.h>

#define DEV __device__ __forceinline__

typedef unsigned short u16;
typedef unsigned int u32;
typedef float f32x4 __attribute__((ext_vector_type(4)));
typedef short s16x8 __attribute__((ext_vector_type(8)));

static constexpr int Bb = 4, Ll = 2048, DM = 1024, DI = 2048, NH = 32;
static constexpr int CD = 2304;       // conv dim
static constexpr int NP = 4384;       // d_in_proj
static constexpr int NP_PAD = 4480;   // 35*128
static constexpr int BL = Bb * Ll;    // 8192
static constexpr int NC = 32;         // chunks per sequence (L/64)

DEV float u2f(u16 s) { return __uint_as_float(((u32)s) << 16); }
DEV u16 f2bu(float f) {
  __hip_bfloat16 h = __float2bfloat16(f);
  u16 s; __builtin_memcpy(&s, &h, 2); return s;
}
DEV float blo(u32 u) { return __uint_as_float(u << 16); }
DEV float bhi(u32 u) { return __uint_as_float(u & 0xffff0000u); }

// XOR-swizzled LDS index for [rows][64] and [rows][128] bf16 tiles (k-minor).
DEV int swz64(int r, int k)  { return r * 64  + ((((k >> 3) ^ (r & 7))) << 3) + (k & 7); }

DEV void gl_lds16(const u16* g, u16* l) {
  __builtin_amdgcn_global_load_lds(
      (const __attribute__((address_space(1))) u32*)g,
      (__attribute__((address_space(3))) u32*)l, 16, 0, 0);
}

// ---------------- weight convert (+row pad) ----------------
__global__ __launch_bounds__(256) void cvt_pad(const float* __restrict__ src,
    u16* __restrict__ dst, int total, int cols, int realRows) {
  int i = blockIdx.x * 256 + threadIdx.x;
  if (i >= total) return;
  int r = i / cols;
  dst[i] = (r < realRows) ? f2bu(src[i]) : (u16)0;
}

// ---------------- LayerNorm -> bf16 ----------------
__global__ __launch_bounds__(256) void ln_kernel(const float* __restrict__ x,
    const float* __restrict__ w, const float* __restrict__ bia, u16* __restrict__ u) {
  int row = blockIdx.x, tid = threadIdx.x;
  const float4* xr = (const float4*)(x + (size_t)row * DM);
  float4 v = xr[tid];
  float s = v.x + v.y + v.z + v.w;
  float s2 = v.x*v.x + v.y*v.y + v.z*v.z + v.w*v.w;
  #pragma unroll
  for (int o = 32; o; o >>= 1) { s += __shfl_down(s, o); s2 += __shfl_down(s2, o); }
  __shared__ float rs[4], rs2[4];
  int wv = tid >> 6, ln = tid & 63;
  if (ln == 0) { rs[wv] = s; rs2[wv] = s2; }
  __syncthreads();
  s = rs[0] + rs[1] + rs[2] + rs[3];
  s2 = rs2[0] + rs2[1] + rs2[2] + rs2[3];
  float mu = s * (1.f / DM);
  float var = s2 * (1.f / DM) - mu * mu;
  float inv = rsqrtf(var + 1e-5f);
  float4 wv4 = ((const float4*)w)[tid], bv4 = ((const float4*)bia)[tid];
  ushort4 o;
  o.x = f2bu((v.x - mu) * inv * wv4.x + bv4.x);
  o.y = f2bu((v.y - mu) * inv * wv4.y + bv4.y);
  o.z = f2bu((v.z - mu) * inv * wv4.z + bv4.z);
  o.w = f2bu((v.w - mu) * inv * wv4.w + bv4.w);
  ((ushort4*)(u + (size_t)row * DM))[tid] = o;
}

// ---------------- bf16 MFMA GEMM:  C[m][n] = sum_k A[m][k]*B[n][k] ----------------
// MODE 0: in_proj — split bf16 writes to zbuf / xbc / dtraw by blockIdx.y region
// MODE 1: out_proj — f32 out + residual
template<int MODE>
__global__ __launch_bounds__(256) void gemm_nt(const u16* __restrict__ A,
    const u16* __restrict__ Bw, void* __restrict__ o0, void* __restrict__ o1,
    void* __restrict__ o2, const float* __restrict__ resid, int N, int K) {
  __shared__ u16 sA[128 * 32];
  __shared__ u16 sB[128 * 32];
  int tid = threadIdx.x, wid = tid >> 6, lane = tid & 63;
  int m0 = blockIdx.x * 128, n0 = blockIdx.y * 128;
  int wm = (wid >> 1) * 64, wn = (wid & 1) * 64;
  f32x4 acc[4][4];
  #pragma unroll
  for (int i = 0; i < 4; i++)
    #pragma unroll
    for (int j = 0; j < 4; j++) acc[i][j] = (f32x4){0.f, 0.f, 0.f, 0.f};
  int rA = wid * 32 + (lane >> 2);
  int cA = (lane & 3) * 8;
  const u16* gA = A + (size_t)(m0 + rA) * K + cA;
  const u16* gB = Bw + (size_t)(n0 + rA) * K + cA;
  u16* lA0 = &sA[(wid * 2 + 0) * 512]; u16* lA1 = &sA[(wid * 2 + 1) * 512];
  u16* lB0 = &sB[(wid * 2 + 0) * 512]; u16* lB1 = &sB[(wid * 2 + 1) * 512];
  int fr = lane & 15, fk = (lane >> 4) * 8, fq = lane >> 4;
  for (int kk = 0; kk < K; kk += 32) {
    gl_lds16(gA + kk, lA0);
    gl_lds16(gA + (size_t)16 * K + kk, lA1);
    gl_lds16(gB + kk, lB0);
    gl_lds16(gB + (size_t)16 * K + kk, lB1);
    __syncthreads();
    s16x8 af[4], bfr[4];
    #pragma unroll
    for (int i = 0; i < 4; i++) af[i] = *(const s16x8*)&sA[(wm + i * 16 + fr) * 32 + fk];
    #pragma unroll
    for (int i = 0; i < 4; i++) bfr[i] = *(const s16x8*)&sB[(wn + i * 16 + fr) * 32 + fk];
    #pragma unroll
    for (int mi = 0; mi < 4; mi++)
      #pragma unroll
      for (int ni = 0; ni < 4; ni++)
        acc[mi][ni] = __builtin_amdgcn_mfma_f32_16x16x32_bf16(af[mi], bfr[ni], acc[mi][ni], 0, 0, 0);
    __syncthreads();
  }
  // epilogue
  if (MODE == 0) {
    const int by = blockIdx.y;
    u16* ob; int ostr, cb0;
    if (by < 16)      { ob = (u16*)o0; ostr = 2048; cb0 = 0; }
    else if (by < 34) { ob = (u16*)o1; ostr = 2304; cb0 = 2048; }
    else              { ob = (u16*)o2; ostr = 32;   cb0 = 4352; }
    #pragma unroll
    for (int mi = 0; mi < 4; mi++) {
      #pragma unroll
      for (int ni = 0; ni < 4; ni++) {
        int col = n0 + wn + ni * 16 + fr;
        int c = col - cb0;
        if (by == 34 && c >= 32) continue;
        #pragma unroll
        for (int r = 0; r < 4; r++) {
          int row = m0 + wm + mi * 16 + fq * 4 + r;
          ob[(size_t)row * ostr + c] = f2bu(acc[mi][ni][r]);
        }
      }
    }
  } else {
    float* of = (float*)o0;
    #pragma unroll
    for (int mi = 0; mi < 4; mi++) {
      #pragma unroll
      for (int ni = 0; ni < 4; ni++) {
        int col = n0 + wn + ni * 16 + fr;
        #pragma unroll
        for (int r = 0; r < 4; r++) {
          int row = m0 + wm + mi * 16 + fq * 4 + r;
          of[(size_t)row * N + col] = acc[mi][ni][r] + resid[(size_t)row * N + col];
        }
      }
    }
  }
}

// ---------------- depthwise causal conv(4) + SiLU (reads xbc, stride CD) ----------------
__global__ __launch_bounds__(256) void conv_silu(const u16* __restrict__ xbc,
    const float* __restrict__ cw, const float* __restrict__ cb, u16* __restrict__ out) {
  int i = blockIdx.x * 256 + threadIdx.x;
  if (i >= BL * CD) return;
  int c = i % CD;
  int bl = i / CD;
  int l = bl % Ll;
  float acc = cb[c];
  #pragma unroll
  for (int k = 0; k < 4; ++k) {
    int ls = l - 3 + k;
    if (ls >= 0) acc += cw[c * 4 + k] * u2f(xbc[(size_t)(bl - 3 + k) * CD + c]);
  }
  float sg = 1.f / (1.f + __expf(-acc));
  out[i] = f2bu(acc * sg);
}

// ---------------- dt = softplus(raw+bias); s = intra-chunk cumsum(dt*A) ----------------
__global__ __launch_bounds__(256) void dt_cumsum(const u16* __restrict__ dtraw,
    const float* __restrict__ dtb, const float* __restrict__ alog,
    float* __restrict__ dtv, float* __restrict__ sv) {
  int wid = threadIdx.x >> 6, lane = threadIdx.x & 63;
  int g = blockIdx.x * 4 + wid;          // (b,h,c) flattened, 4096 total
  int b = g >> 10, h = (g >> 5) & 31, c = g & 31;
  int t = c * 64 + lane;
  float raw = u2f(dtraw[(size_t)(b * Ll + t) * 32 + h]);
  float v = raw + dtb[h];
  float dt = (v > 20.f) ? v : log1pf(__expf(v));
  float a = -dt * __expf(alog[h]);
  float s = a;
  #pragma unroll
  for (int o = 1; o < 64; o <<= 1) {
    float u = __shfl_up(s, o);
    if (lane >= o) s += u;
  }
  int idx = (b * 32 + h) * Ll + t;
  dtv[idx] = dt;
  sv[idx] = s;
}

// ---------------- per-(b,h): chunk-state GEMM + inter-chunk scan ----------------
// H_c[p][n] = sum_j exp(s_last-s_j)*dt_j*x_j[p] * B_j[n];  hs = exp(s_last)*hs + H_c
// stores pre-update hs (= h_start for chunk c) as bf16.
__global__ __launch_bounds__(256) void state_scan(const u16* __restrict__ conv,
    const float* __restrict__ dtv, const float* __restrict__ sv,
    u16* __restrict__ hstart) {
  __shared__ u16 xsT[64 * 64];   // [p][j] swizzled, scaled
  __shared__ u16 BT[128 * 64];   // [n][j] swizzled
  int bh = blockIdx.x; int b = bh >> 5, h = bh & 31;
  int tid = threadIdx.x, w = tid >> 6, lane = tid & 63;
  int fr = lane & 15, fq = lane >> 4;
  int j = tid & 63, pg = tid >> 6;
  const float* svb = sv + (size_t)bh * Ll;
  const float* dvb = dtv + (size_t)bh * Ll;
  const u16* cvb = conv + (size_t)b * Ll * CD;
  u16* hsb = hstart + (size_t)bh * NC * 8192;
  f32x4 hs[4][2];
  #pragma unroll
  for (int mi = 0; mi < 4; mi++)
    #pragma unroll
    for (int ni = 0; ni < 2; ni++) hs[mi][ni] = (f32x4){0.f, 0.f, 0.f, 0.f};

  for (int c = 0; c < NC; c++) {
    int tb = c * 64;
    float s_last = svb[tb + 63];
    float wj = __expf(s_last - svb[tb + j]) * dvb[tb + j];
    const u16* rowp = cvb + (size_t)(tb + j) * CD;
    // stage scaled x^T
    #pragma unroll
    for (int rep = 0; rep < 2; rep++) {
      int p0 = rep * 32 + pg * 8;
      uint4 v = *(const uint4*)(rowp + h * 64 + p0);
      u32 va[4] = {v.x, v.y, v.z, v.w};
      #pragma unroll
      for (int e = 0; e < 4; e++) {
        xsT[swz64(p0 + 2 * e, j)]     = f2bu(blo(va[e]) * wj);
        xsT[swz64(p0 + 2 * e + 1, j)] = f2bu(bhi(va[e]) * wj);
      }
    }
    // stage B^T
    #pragma unroll
    for (int rep = 0; rep < 4; rep++) {
      int n0 = rep * 32 + pg * 8;
      uint4 v = *(const uint4*)(rowp + DI + n0);
      u32 va[4] = {v.x, v.y, v.z, v.w};
      #pragma unroll
      for (int e = 0; e < 4; e++) {
        BT[swz64(n0 + 2 * e, j)]     = (u16)(va[e] & 0xffffu);
        BT[swz64(n0 + 2 * e + 1, j)] = (u16)(va[e] >> 16);
      }
    }
    __syncthreads();
    f32x4 acc[4][2];
    #pragma unroll
    for (int mi = 0; mi < 4; mi++)
      #pragma unroll
      for (int ni = 0; ni < 2; ni++) acc[mi][ni] = (f32x4){0.f, 0.f, 0.f, 0.f};
    #pragma unroll
    for (int ks = 0; ks < 2; ks++) {
      int k8 = ks * 4 + fq;
      s16x8 bfv[2];
      #pragma unroll
      for (int ni = 0; ni < 2; ni++) {
        int rb = w * 32 + ni * 16 + fr;
        bfv[ni] = *(const s16x8*)&BT[rb * 64 + ((k8 ^ (rb & 7)) << 3)];
      }
      #pragma unroll
      for (int mi = 0; mi < 4; mi++) {
        int ra = mi * 16 + fr;
        s16x8 af = *(const s16x8*)&xsT[ra * 64 + ((k8 ^ (ra & 7)) << 3)];
        #pragma unroll
        for (int ni = 0; ni < 2; ni++)
          acc[mi][ni] = __builtin_amdgcn_mfma_f32_16x16x32_bf16(af, bfv[ni], acc[mi][ni], 0, 0, 0);
      }
    }
    float e = __expf(s_last);
    u16* hc = hsb + (size_t)c * 8192;
    #pragma unroll
    for (int mi = 0; mi < 4; mi++) {
      #pragma unroll
      for (int ni = 0; ni < 2; ni++) {
        int p = mi * 16 + fq * 4;
        int n = w * 32 + ni * 16 + fr;
        #pragma unroll
        for (int r = 0; r < 4; r++) {
          hc[(size_t)(p + r) * 128 + n] = f2bu(hs[mi][ni][r]);
          hs[mi][ni][r] = e * hs[mi][ni][r] + acc[mi][ni][r];
        }
      }
    }
    __syncthreads();
  }
}

// ---------------- per-(b,h,c): G=C·B^T, mask, Yintra=M·x, Yinter=exp(s)·(C·h^T), +D·x ----------------
__global__ __launch_bounds__(256) void chunk_out(const u16* __restrict__ conv,
    const u16* __restrict__ hstart, const float* __restrict__ dtv,
    const float* __restrict__ sv, const float* __restrict__ Dp,
    u16* __restrict__ yb) {
  __shared__ u16 Ct[64 * 128];   // C tile [i][n], swizzled via pre-swizzled gl_lds src
  __shared__ u16 Bt[64 * 128];   // B tile [j][n]
  __shared__ u16 Hs[64 * 128];   // h_start [p][n]
  __shared__ u16 xT[64 * 64];    // x^T [p][j], swz64 (reg-staged)
  __shared__ u16 Ml[64 * 64];    // M [i][j], swz64
  __shared__ float svl[64], dtl[64], pexl[64];
  int gid = blockIdx.x;
  int c = gid & 31, h = (gid >> 5) & 31, b = gid >> 10;
  int tid = threadIdx.x, w = tid >> 6, lane = tid & 63;
  int fr = lane & 15, fq = lane >> 4;
  int tb = c * 64;
  const u16* cvb = conv + ((size_t)b * Ll + tb) * CD;
  const u16* hsrc = hstart + (((size_t)(b * 32 + h)) * NC + c) * 8192;
  // gl_lds staging with pre-swizzled per-lane source (involution XOR)
  #pragma unroll
  for (int qq = 0; qq < 4; qq++) {
    int q = w * 4 + qq;
    int i = q * 4 + (lane >> 4);
    int s = lane & 15;
    int kc = ((s ^ (i & 7)) << 3);
    gl_lds16(cvb + (size_t)i * CD + 2176 + kc, &Ct[q * 512]);
    gl_lds16(cvb + (size_t)i * CD + 2048 + kc, &Bt[q * 512]);
    gl_lds16(hsrc + (size_t)i * 128 + kc, &Hs[q * 512]);
  }
  // x^T reg-staged transpose (unscaled)
  {
    int j = tid & 63, pg = tid >> 6;
    const u16* rowp = cvb + (size_t)j * CD + h * 64;
    #pragma unroll
    for (int rep = 0; rep < 2; rep++) {
      int p0 = rep * 32 + pg * 8;
      uint4 v = *(const uint4*)(rowp + p0);
      u32 va[4] = {v.x, v.y, v.z, v.w};
      #pragma unroll
      for (int e = 0; e < 4; e++) {
        xT[swz64(p0 + 2 * e, j)]     = (u16)(va[e] & 0xffffu);
        xT[swz64(p0 + 2 * e + 1, j)] = (u16)(va[e] >> 16);
      }
    }
  }
  if (tid < 64) {
    float s = sv[(size_t)(b * 32 + h) * Ll + tb + tid];
    svl[tid] = s;
    pexl[tid] = __expf(s);
    dtl[tid] = dtv[(size_t)(b * 32 + h) * Ll + tb + tid];
  }
  __syncthreads();
  // GEMM-2: G[i][j] = sum_n C[i][n]*B[j][n], wave owns j-slice of 16
  f32x4 g2[4];
  #pragma unroll
  for (int mi = 0; mi < 4; mi++) g2[mi] = (f32x4){0.f, 0.f, 0.f, 0.f};
  int wj = w * 16;
  #pragma unroll
  for (int ks = 0; ks < 4; ks++) {
    int k8 = ks * 4 + fq;
    int rb = wj + fr;
    s16x8 bf = *(const s16x8*)&Bt[rb * 128 + ((k8 ^ (rb & 7)) << 3)];
    #pragma unroll
    for (int mi = 0; mi < 4; mi++) {
      int ra = mi * 16 + fr;
      s16x8 af = *(const s16x8*)&Ct[ra * 128 + ((k8 ^ (ra & 7)) << 3)];
      g2[mi] = __builtin_amdgcn_mfma_f32_16x16x32_bf16(af, bf, g2[mi], 0, 0, 0);
    }
  }
  // mask + scale -> M (bf16, swz64)
  #pragma unroll
  for (int mi = 0; mi < 4; mi++) {
    int jj = wj + fr;
    #pragma unroll
    for (int r = 0; r < 4; r++) {
      int ii = mi * 16 + fq * 4 + r;
      float v = 0.f;
      if (jj <= ii) v = g2[mi][r] * __expf(svl[ii] - svl[jj]) * dtl[jj];
      Ml[swz64(ii, jj)] = f2bu(v);
    }
  }
  __syncthreads();
  // GEMM-3 (M·x, K=64) and GEMM-4 (C·h^T, K=128, scaled by exp(s_i) in epilogue)
  f32x4 aY[4], a4[4];
  #pragma unroll
  for (int mi = 0; mi < 4; mi++) { aY[mi] = (f32x4){0.f, 0.f, 0.f, 0.f}; a4[mi] = (f32x4){0.f, 0.f, 0.f, 0.f}; }
  int wp = w * 16;
  #pragma unroll
  for (int ks = 0; ks < 2; ks++) {
    int k8 = ks * 4 + fq;
    int rb = wp + fr;
    s16x8 bf = *(const s16x8*)&xT[rb * 64 + ((k8 ^ (rb & 7)) << 3)];
    #pragma unroll
    for (int mi = 0; mi < 4; mi++) {
      int ra = mi * 16 + fr;
      s16x8 af = *(const s16x8*)&Ml[ra * 64 + ((k8 ^ (ra & 7)) << 3)];
      aY[mi] = __builtin_amdgcn_mfma_f32_16x16x32_bf16(af, bf, aY[mi], 0, 0, 0);
    }
  }
  #pragma unroll
  for (int ks = 0; ks < 4; ks++) {
    int k8 = ks * 4 + fq;
    int rb = wp + fr;
    s16x8 bf = *(const s16x8*)&Hs[rb * 128 + ((k8 ^ (rb & 7)) << 3)];
    #pragma unroll
    for (int mi = 0; mi < 4; mi++) {
      int ra = mi * 16 + fr;
      s16x8 af = *(const s16x8*)&Ct[ra * 128 + ((k8 ^ (ra & 7)) << 3)];
      a4[mi] = __builtin_amdgcn_mfma_f32_16x16x32_bf16(af, bf, a4[mi], 0, 0, 0);
    }
  }
  // epilogue: y = Yintra + exp(s_i)*Yinter + D*x
  float Dh = Dp[h];
  u16* yrow = yb + ((size_t)b * Ll + tb) * DI + h * 64;
  #pragma unroll
  for (int mi = 0; mi < 4; mi++) {
    int p = wp + fr;
    #pragma unroll
    for (int r = 0; r < 4; r++) {
      int i = mi * 16 + fq * 4 + r;
      float xh = u2f(cvb[(size_t)i * CD + h * 64 + p]);
      yrow[(size_t)i * DI + p] = f2bu(aY[mi][r] + pexl[i] * a4[mi][r] + Dh * xh);
    }
  }
}

// ---------------- g = y*silu(z), RMSNorm, *rms_w ----------------
__global__ __launch_bounds__(256) void gate_rms(const u16* __restrict__ y,
    const u16* __restrict__ zbuf, const float* __restrict__ rw, u16* __restrict__ g) {
  int bl = blockIdx.x, tid = threadIdx.x;
  uint4 yv = ((const uint4*)(y + (size_t)bl * DI))[tid];
  uint4 zv = ((const uint4*)(zbuf + (size_t)bl * DI))[tid];
  u32 ya[4] = {yv.x, yv.y, yv.z, yv.w};
  u32 za[4] = {zv.x, zv.y, zv.z, zv.w};
  float gv[8];
  float ss = 0.f;
  #pragma unroll
  for (int jx = 0; jx < 4; jx++) {
    float y0 = blo(ya[jx]), y1 = bhi(ya[jx]);
    float z0 = blo(za[jx]), z1 = bhi(za[jx]);
    float s0 = z0 / (1.f + __expf(-z0));
    float s1 = z1 / (1.f + __expf(-z1));
    gv[jx * 2] = y0 * s0; gv[jx * 2 + 1] = y1 * s1;
    ss += gv[jx * 2] * gv[jx * 2] + gv[jx * 2 + 1] * gv[jx * 2 + 1];
  }
  #pragma unroll
  for (int o = 32; o; o >>= 1) ss += __shfl_down(ss, o);
  __shared__ float red[4];
  int wv = tid >> 6, ln = tid & 63;
  if (ln == 0) red[wv] = ss;
  __syncthreads();
  ss = red[0] + red[1] + red[2] + red[3];
  float scale = rsqrtf(ss * (1.f / DI) + 1e-5f);
  const float* rwp = rw + tid * 8;
  ushort4 o0, o1;
  o0.x = f2bu(gv[0] * scale * rwp[0]); o0.y = f2bu(gv[1] * scale * rwp[1]);
  o0.z = f2bu(gv[2] * scale * rwp[2]); o0.w = f2bu(gv[3] * scale * rwp[3]);
  o1.x = f2bu(gv[4] * scale * rwp[4]); o1.y = f2bu(gv[5] * scale * rwp[5]);
  o1.z = f2bu(gv[6] * scale * rwp[6]); o1.w = f2bu(gv[7] * scale * rwp[7]);
  ushort4* gp = (ushort4*)(g + (size_t)bl * DI + tid * 8);
  gp[0] = o0; gp[1] = o1;
}

extern "C" void kernel_launch(void* const* d_in, const int* in_sizes, int n_in,
                              void* d_out, int out_size, void* d_ws, size_t ws_size,
                              hipStream_t stream) {
  const float* x    = (const float*)d_in[0];
  const float* lnw  = (const float*)d_in[1];
  const float* lnb  = (const float*)d_in[2];
  const float* w1   = (const float*)d_in[3];
  const float* cw   = (const float*)d_in[4];
  const float* cb   = (const float*)d_in[5];
  const float* dtb  = (const float*)d_in[6];
  const float* alog = (const float*)d_in[7];
  const float* Dp   = (const float*)d_in[8];
  const float* rw   = (const float*)d_in[9];
  const float* w2   = (const float*)d_in[10];

  // workspace layout (bytes); overlays are stream-order-safe:
  //   ub/W1b (dead after in_proj) under conv; xbc+dtraw (dead after conv/cumsum)
  //   under hstart; gb (written after hstart is dead) over hstart.
  char* ws = (char*)d_ws;
  u16*   ub     = (u16*)(ws + 0);            // 16,777,216
  u16*   W1b    = (u16*)(ws + 16777216);     // 9,175,040
  u16*   conv   = (u16*)(ws + 0);            // 37,748,736 (overlays ub+W1b)
  u16*   zbuf   = (u16*)(ws + 37748736);     // 33,554,432
  u16*   xbc    = (u16*)(ws + 71303168);     // 37,748,736
  u16*   dtraw  = (u16*)(ws + 109051904);    // 524,288
  u16*   hstart = (u16*)(ws + 71303168);     // 67,108,864 (overlays xbc+dtraw)
  u16*   gb     = (u16*)(ws + 71303168);     // 33,554,432 (overlays hstart)
  float* dtv    = (float*)(ws + 138412032);  // 1,048,576
  float* sv     = (float*)(ws + 139460608);  // 1,048,576
  u16*   yb     = (u16*)(ws + 140509184);    // 33,554,432
  u16*   W2b    = (u16*)(ws + 174063616);    // 4,194,304 -> end 178,257,920
  if (ws_size < 178257920u) return;

  float* out = (float*)d_out;

  cvt_pad<<<(NP_PAD * 1024) / 256, 256, 0, stream>>>(w1, W1b, NP_PAD * 1024, 1024, NP);
  cvt_pad<<<(1024 * 2048) / 256, 256, 0, stream>>>(w2, W2b, 1024 * 2048, 2048, 1024);
  ln_kernel<<<BL, 256, 0, stream>>>(x, lnw, lnb, ub);
  gemm_nt<0><<<dim3(64, 35), 256, 0, stream>>>(ub, W1b, zbuf, xbc, dtraw, nullptr, NP, 1024);
  conv_silu<<<(BL * CD) / 256, 256, 0, stream>>>(xbc, cw, cb, conv);
  dt_cumsum<<<1024, 256, 0, stream>>>(dtraw, dtb, alog, dtv, sv);
  state_scan<<<128, 256, 0, stream>>>(conv, dtv, sv, hstart);
  chunk_out<<<4096, 256, 0, stream>>>(conv, hstart, dtv, sv, Dp, yb);
  gate_rms<<<BL, 256, 0, stream>>>(yb, zbuf, rw, gb);
  gemm_nt<1><<<dim3(64, 8), 256, 0, stream>>>(gb, W2b, out, nullptr, nullptr, x, 1024, 2048);
}

// Round 5
// 383.717 us; speedup vs baseline: 4.3144x; 1.0482x over previous
//
#include <hip/hip_runtime.h>
#include <hip/hip_bf16.h>

#define DEV __device__ __forceinline__

typedef unsigned short u16;
typedef unsigned int u32;
typedef float f32x4 __attribute__((ext_vector_type(4)));
typedef short s16x8 __attribute__((ext_vector_type(8)));

static constexpr int Bb = 4, Ll = 2048, DM = 1024, DI = 2048, NH = 32;
static constexpr int CD = 2304;       // conv dim
static constexpr int NP = 4384;       // d_in_proj
static constexpr int NP_PAD = 4480;   // 35*128
static constexpr int BL = Bb * Ll;    // 8192
static constexpr int NC = 32;         // chunks per sequence (L/64)

DEV float u2f(u16 s) { return __uint_as_float(((u32)s) << 16); }
DEV u16 f2bu(float f) {
  __hip_bfloat16 h = __float2bfloat16(f);
  u16 s; __builtin_memcpy(&s, &h, 2); return s;
}
DEV float blo(u32 u) { return __uint_as_float(u << 16); }
DEV float bhi(u32 u) { return __uint_as_float(u & 0xffff0000u); }

// XOR-swizzled LDS index for [rows][64] bf16 tiles (k-minor).
DEV int swz64(int r, int k)  { return r * 64  + ((((k >> 3) ^ (r & 7))) << 3) + (k & 7); }

DEV void gl_lds16(const u16* g, u16* l) {
  __builtin_amdgcn_global_load_lds(
      (const __attribute__((address_space(1))) u32*)g,
      (__attribute__((address_space(3))) u32*)l, 16, 0, 0);
}

// ---------------- weight convert (+row pad) ----------------
__global__ __launch_bounds__(256) void cvt_pad(const float* __restrict__ src,
    u16* __restrict__ dst, int total, int cols, int realRows) {
  int i = blockIdx.x * 256 + threadIdx.x;
  if (i >= total) return;
  int r = i / cols;
  dst[i] = (r < realRows) ? f2bu(src[i]) : (u16)0;
}

// ---------------- LayerNorm -> bf16 ----------------
__global__ __launch_bounds__(256) void ln_kernel(const float* __restrict__ x,
    const float* __restrict__ w, const float* __restrict__ bia, u16* __restrict__ u) {
  int row = blockIdx.x, tid = threadIdx.x;
  const float4* xr = (const float4*)(x + (size_t)row * DM);
  float4 v = xr[tid];
  float s = v.x + v.y + v.z + v.w;
  float s2 = v.x*v.x + v.y*v.y + v.z*v.z + v.w*v.w;
  #pragma unroll
  for (int o = 32; o; o >>= 1) { s += __shfl_down(s, o); s2 += __shfl_down(s2, o); }
  __shared__ float rs[4], rs2[4];
  int wv = tid >> 6, ln = tid & 63;
  if (ln == 0) { rs[wv] = s; rs2[wv] = s2; }
  __syncthreads();
  s = rs[0] + rs[1] + rs[2] + rs[3];
  s2 = rs2[0] + rs2[1] + rs2[2] + rs2[3];
  float mu = s * (1.f / DM);
  float var = s2 * (1.f / DM) - mu * mu;
  float inv = rsqrtf(var + 1e-5f);
  float4 wv4 = ((const float4*)w)[tid], bv4 = ((const float4*)bia)[tid];
  ushort4 o;
  o.x = f2bu((v.x - mu) * inv * wv4.x + bv4.x);
  o.y = f2bu((v.y - mu) * inv * wv4.y + bv4.y);
  o.z = f2bu((v.z - mu) * inv * wv4.z + bv4.z);
  o.w = f2bu((v.w - mu) * inv * wv4.w + bv4.w);
  ((ushort4*)(u + (size_t)row * DM))[tid] = o;
}

// ---------------- bf16 MFMA GEMM:  C[m][n] = sum_k A[m][k]*B[n][k] ----------------
// MODE 0: in_proj — split bf16 writes to zbuf / xbc / dtraw by blockIdx.y region
// MODE 1: out_proj — f32 out + residual
template<int MODE>
__global__ __launch_bounds__(256) void gemm_nt(const u16* __restrict__ A,
    const u16* __restrict__ Bw, void* __restrict__ o0, void* __restrict__ o1,
    void* __restrict__ o2, const float* __restrict__ resid, int N, int K) {
  __shared__ u16 sA[128 * 32];
  __shared__ u16 sB[128 * 32];
  int tid = threadIdx.x, wid = tid >> 6, lane = tid & 63;
  int m0 = blockIdx.x * 128, n0 = blockIdx.y * 128;
  int wm = (wid >> 1) * 64, wn = (wid & 1) * 64;
  f32x4 acc[4][4];
  #pragma unroll
  for (int i = 0; i < 4; i++)
    #pragma unroll
    for (int j = 0; j < 4; j++) acc[i][j] = (f32x4){0.f, 0.f, 0.f, 0.f};
  int rA = wid * 32 + (lane >> 2);
  int cA = (lane & 3) * 8;
  const u16* gA = A + (size_t)(m0 + rA) * K + cA;
  const u16* gB = Bw + (size_t)(n0 + rA) * K + cA;
  u16* lA0 = &sA[(wid * 2 + 0) * 512]; u16* lA1 = &sA[(wid * 2 + 1) * 512];
  u16* lB0 = &sB[(wid * 2 + 0) * 512]; u16* lB1 = &sB[(wid * 2 + 1) * 512];
  int fr = lane & 15, fk = (lane >> 4) * 8, fq = lane >> 4;
  for (int kk = 0; kk < K; kk += 32) {
    gl_lds16(gA + kk, lA0);
    gl_lds16(gA + (size_t)16 * K + kk, lA1);
    gl_lds16(gB + kk, lB0);
    gl_lds16(gB + (size_t)16 * K + kk, lB1);
    __syncthreads();
    s16x8 af[4], bfr[4];
    #pragma unroll
    for (int i = 0; i < 4; i++) af[i] = *(const s16x8*)&sA[(wm + i * 16 + fr) * 32 + fk];
    #pragma unroll
    for (int i = 0; i < 4; i++) bfr[i] = *(const s16x8*)&sB[(wn + i * 16 + fr) * 32 + fk];
    #pragma unroll
    for (int mi = 0; mi < 4; mi++)
      #pragma unroll
      for (int ni = 0; ni < 4; ni++)
        acc[mi][ni] = __builtin_amdgcn_mfma_f32_16x16x32_bf16(af[mi], bfr[ni], acc[mi][ni], 0, 0, 0);
    __syncthreads();
  }
  // epilogue
  if (MODE == 0) {
    const int by = blockIdx.y;
    u16* ob; int ostr, cb0;
    if (by < 16)      { ob = (u16*)o0; ostr = 2048; cb0 = 0; }
    else if (by < 34) { ob = (u16*)o1; ostr = 2304; cb0 = 2048; }
    else              { ob = (u16*)o2; ostr = 32;   cb0 = 4352; }
    #pragma unroll
    for (int mi = 0; mi < 4; mi++) {
      #pragma unroll
      for (int ni = 0; ni < 4; ni++) {
        int col = n0 + wn + ni * 16 + fr;
        int c = col - cb0;
        if (by == 34 && c >= 32) continue;
        #pragma unroll
        for (int r = 0; r < 4; r++) {
          int row = m0 + wm + mi * 16 + fq * 4 + r;
          ob[(size_t)row * ostr + c] = f2bu(acc[mi][ni][r]);
        }
      }
    }
  } else {
    float* of = (float*)o0;
    #pragma unroll
    for (int mi = 0; mi < 4; mi++) {
      #pragma unroll
      for (int ni = 0; ni < 4; ni++) {
        int col = n0 + wn + ni * 16 + fr;
        #pragma unroll
        for (int r = 0; r < 4; r++) {
          int row = m0 + wm + mi * 16 + fq * 4 + r;
          of[(size_t)row * N + col] = acc[mi][ni][r] + resid[(size_t)row * N + col];
        }
      }
    }
  }
}

// ---------------- depthwise causal conv(4) + SiLU (reads xbc, stride CD) ----------------
__global__ __launch_bounds__(256) void conv_silu(const u16* __restrict__ xbc,
    const float* __restrict__ cw, const float* __restrict__ cb, u16* __restrict__ out) {
  int i = blockIdx.x * 256 + threadIdx.x;
  if (i >= BL * CD) return;
  int c = i % CD;
  int bl = i / CD;
  int l = bl % Ll;
  float acc = cb[c];
  #pragma unroll
  for (int k = 0; k < 4; ++k) {
    int ls = l - 3 + k;
    if (ls >= 0) acc += cw[c * 4 + k] * u2f(xbc[(size_t)(bl - 3 + k) * CD + c]);
  }
  float sg = 1.f / (1.f + __expf(-acc));
  out[i] = f2bu(acc * sg);
}

// ---------------- dt = softplus(raw+bias); s = intra-chunk cumsum(dt*A) ----------------
__global__ __launch_bounds__(256) void dt_cumsum(const u16* __restrict__ dtraw,
    const float* __restrict__ dtb, const float* __restrict__ alog,
    float* __restrict__ dtv, float* __restrict__ sv) {
  int wid = threadIdx.x >> 6, lane = threadIdx.x & 63;
  int g = blockIdx.x * 4 + wid;          // (b,h,c) flattened, 4096 total
  int b = g >> 10, h = (g >> 5) & 31, c = g & 31;
  int t = c * 64 + lane;
  float raw = u2f(dtraw[(size_t)(b * Ll + t) * 32 + h]);
  float v = raw + dtb[h];
  float dt = (v > 20.f) ? v : log1pf(__expf(v));
  float a = -dt * __expf(alog[h]);
  float s = a;
  #pragma unroll
  for (int o = 1; o < 64; o <<= 1) {
    float u = __shfl_up(s, o);
    if (lane >= o) s += u;
  }
  int idx = (b * 32 + h) * Ll + t;
  dtv[idx] = dt;
  sv[idx] = s;
}

// ---------------- per-(b,h,c): chunk-state GEMM -> S_c[p][n] (bf16) ----------------
// S_c[p][n] = sum_j exp(s_last-s_j)*dt_j * x_j[p] * B_j[n]
__global__ __launch_bounds__(256) void chunk_state(const u16* __restrict__ conv,
    const float* __restrict__ dtv, const float* __restrict__ sv,
    u16* __restrict__ S) {
  __shared__ u16 xsT[64 * 64];   // [p][j] swizzled, scaled
  __shared__ u16 BT[128 * 64];   // [n][j] swizzled
  int gid = blockIdx.x;          // b*1024 + h*32 + c
  int c = gid & 31, h = (gid >> 5) & 31, b = gid >> 10;
  int bh = b * 32 + h;
  int tid = threadIdx.x, w = tid >> 6, lane = tid & 63;
  int fr = lane & 15, fq = lane >> 4;
  int j = tid & 63, pg = tid >> 6;
  int tb = c * 64;
  const float* svb = sv + (size_t)bh * Ll + tb;
  const float* dvb = dtv + (size_t)bh * Ll + tb;
  const u16* cvb = conv + (size_t)(b * Ll + tb) * CD;
  float s_last = svb[63];
  float wj = __expf(s_last - svb[j]) * dvb[j];
  const u16* rowp = cvb + (size_t)j * CD;
  // stage scaled x^T
  #pragma unroll
  for (int rep = 0; rep < 2; rep++) {
    int p0 = rep * 32 + pg * 8;
    uint4 v = *(const uint4*)(rowp + h * 64 + p0);
    u32 va[4] = {v.x, v.y, v.z, v.w};
    #pragma unroll
    for (int e = 0; e < 4; e++) {
      xsT[swz64(p0 + 2 * e, j)]     = f2bu(blo(va[e]) * wj);
      xsT[swz64(p0 + 2 * e + 1, j)] = f2bu(bhi(va[e]) * wj);
    }
  }
  // stage B^T
  #pragma unroll
  for (int rep = 0; rep < 4; rep++) {
    int n0 = rep * 32 + pg * 8;
    uint4 v = *(const uint4*)(rowp + DI + n0);
    u32 va[4] = {v.x, v.y, v.z, v.w};
    #pragma unroll
    for (int e = 0; e < 4; e++) {
      BT[swz64(n0 + 2 * e, j)]     = (u16)(va[e] & 0xffffu);
      BT[swz64(n0 + 2 * e + 1, j)] = (u16)(va[e] >> 16);
    }
  }
  __syncthreads();
  f32x4 acc[4][2];
  #pragma unroll
  for (int mi = 0; mi < 4; mi++)
    #pragma unroll
    for (int ni = 0; ni < 2; ni++) acc[mi][ni] = (f32x4){0.f, 0.f, 0.f, 0.f};
  #pragma unroll
  for (int ks = 0; ks < 2; ks++) {
    int k8 = ks * 4 + fq;
    s16x8 bfv[2];
    #pragma unroll
    for (int ni = 0; ni < 2; ni++) {
      int rb = w * 32 + ni * 16 + fr;
      bfv[ni] = *(const s16x8*)&BT[rb * 64 + ((k8 ^ (rb & 7)) << 3)];
    }
    #pragma unroll
    for (int mi = 0; mi < 4; mi++) {
      int ra = mi * 16 + fr;
      s16x8 af = *(const s16x8*)&xsT[ra * 64 + ((k8 ^ (ra & 7)) << 3)];
      #pragma unroll
      for (int ni = 0; ni < 2; ni++)
        acc[mi][ni] = __builtin_amdgcn_mfma_f32_16x16x32_bf16(af, bfv[ni], acc[mi][ni], 0, 0, 0);
    }
  }
  u16* Sc = S + (size_t)gid * 8192;
  #pragma unroll
  for (int mi = 0; mi < 4; mi++) {
    #pragma unroll
    for (int ni = 0; ni < 2; ni++) {
      int p = mi * 16 + fq * 4;
      int n = w * 32 + ni * 16 + fr;
      #pragma unroll
      for (int r = 0; r < 4; r++)
        Sc[(size_t)(p + r) * 128 + n] = f2bu(acc[mi][ni][r]);
    }
  }
}

// ---------------- state passing: in-place S_c -> h_start_c (pre-chunk state) ----------------
// per element (p,n): acc=0; for c: tmp=S_c; S_c=acc(pre); acc = exp(s_last_c)*acc + tmp
__global__ __launch_bounds__(256) void state_pass(u16* __restrict__ S,
    const float* __restrict__ sv) {
  int bh = blockIdx.x >> 3, q = blockIdx.x & 7;
  int o = q * 1024 + threadIdx.x * 4;
  const float* svb = sv + (size_t)bh * Ll;
  u16* base = S + (size_t)bh * NC * 8192 + o;
  float acc[4] = {0.f, 0.f, 0.f, 0.f};
  for (int c = 0; c < NC; c++) {
    uint2 sc = *(const uint2*)(base + (size_t)c * 8192);
    uint2 pre;
    pre.x = (u32)f2bu(acc[0]) | ((u32)f2bu(acc[1]) << 16);
    pre.y = (u32)f2bu(acc[2]) | ((u32)f2bu(acc[3]) << 16);
    *(uint2*)(base + (size_t)c * 8192) = pre;
    float E = __expf(svb[c * 64 + 63]);
    acc[0] = E * acc[0] + blo(sc.x);
    acc[1] = E * acc[1] + bhi(sc.x);
    acc[2] = E * acc[2] + blo(sc.y);
    acc[3] = E * acc[3] + bhi(sc.y);
  }
}

// ---------------- per-(b,h,c): G=C·B^T, mask, Yintra=M·x, Yinter=exp(s)·(C·h^T), +D·x ----------------
__global__ __launch_bounds__(256) void chunk_out(const u16* __restrict__ conv,
    const u16* __restrict__ hstart, const float* __restrict__ dtv,
    const float* __restrict__ sv, const float* __restrict__ Dp,
    u16* __restrict__ yb) {
  __shared__ u16 Ct[64 * 128];   // C tile [i][n], swizzled via pre-swizzled gl_lds src
  __shared__ u16 Bt[64 * 128];   // B tile [j][n]
  __shared__ u16 Hs[64 * 128];   // h_start [p][n]
  __shared__ u16 xT[64 * 64];    // x^T [p][j], swz64 (reg-staged)
  __shared__ u16 Ml[64 * 64];    // M [i][j], swz64
  __shared__ float svl[64], dtl[64], pexl[64];
  int gid = blockIdx.x;
  int c = gid & 31, h = (gid >> 5) & 31, b = gid >> 10;
  int tid = threadIdx.x, w = tid >> 6, lane = tid & 63;
  int fr = lane & 15, fq = lane >> 4;
  int tb = c * 64;
  const u16* cvb = conv + ((size_t)b * Ll + tb) * CD;
  const u16* hsrc = hstart + (((size_t)(b * 32 + h)) * NC + c) * 8192;
  // gl_lds staging with pre-swizzled per-lane source (involution XOR)
  #pragma unroll
  for (int qq = 0; qq < 4; qq++) {
    int q = w * 4 + qq;
    int i = q * 4 + (lane >> 4);
    int s = lane & 15;
    int kc = ((s ^ (i & 7)) << 3);
    gl_lds16(cvb + (size_t)i * CD + 2176 + kc, &Ct[q * 512]);
    gl_lds16(cvb + (size_t)i * CD + 2048 + kc, &Bt[q * 512]);
    gl_lds16(hsrc + (size_t)i * 128 + kc, &Hs[q * 512]);
  }
  // x^T reg-staged transpose (unscaled)
  {
    int j = tid & 63, pg = tid >> 6;
    const u16* rowp = cvb + (size_t)j * CD + h * 64;
    #pragma unroll
    for (int rep = 0; rep < 2; rep++) {
      int p0 = rep * 32 + pg * 8;
      uint4 v = *(const uint4*)(rowp + p0);
      u32 va[4] = {v.x, v.y, v.z, v.w};
      #pragma unroll
      for (int e = 0; e < 4; e++) {
        xT[swz64(p0 + 2 * e, j)]     = (u16)(va[e] & 0xffffu);
        xT[swz64(p0 + 2 * e + 1, j)] = (u16)(va[e] >> 16);
      }
    }
  }
  if (tid < 64) {
    float s = sv[(size_t)(b * 32 + h) * Ll + tb + tid];
    svl[tid] = s;
    pexl[tid] = __expf(s);
    dtl[tid] = dtv[(size_t)(b * 32 + h) * Ll + tb + tid];
  }
  __syncthreads();
  // GEMM-2: G[i][j] = sum_n C[i][n]*B[j][n], wave owns j-slice of 16
  f32x4 g2[4];
  #pragma unroll
  for (int mi = 0; mi < 4; mi++) g2[mi] = (f32x4){0.f, 0.f, 0.f, 0.f};
  int wj = w * 16;
  #pragma unroll
  for (int ks = 0; ks < 4; ks++) {
    int k8 = ks * 4 + fq;
    int rb = wj + fr;
    s16x8 bf = *(const s16x8*)&Bt[rb * 128 + ((k8 ^ (rb & 7)) << 3)];
    #pragma unroll
    for (int mi = 0; mi < 4; mi++) {
      int ra = mi * 16 + fr;
      s16x8 af = *(const s16x8*)&Ct[ra * 128 + ((k8 ^ (ra & 7)) << 3)];
      g2[mi] = __builtin_amdgcn_mfma_f32_16x16x32_bf16(af, bf, g2[mi], 0, 0, 0);
    }
  }
  // mask + scale -> M (bf16, swz64)
  #pragma unroll
  for (int mi = 0; mi < 4; mi++) {
    int jj = wj + fr;
    #pragma unroll
    for (int r = 0; r < 4; r++) {
      int ii = mi * 16 + fq * 4 + r;
      float v = 0.f;
      if (jj <= ii) v = g2[mi][r] * __expf(svl[ii] - svl[jj]) * dtl[jj];
      Ml[swz64(ii, jj)] = f2bu(v);
    }
  }
  __syncthreads();
  // GEMM-3 (M·x, K=64) and GEMM-4 (C·h^T, K=128, scaled by exp(s_i) in epilogue)
  f32x4 aY[4], a4[4];
  #pragma unroll
  for (int mi = 0; mi < 4; mi++) { aY[mi] = (f32x4){0.f, 0.f, 0.f, 0.f}; a4[mi] = (f32x4){0.f, 0.f, 0.f, 0.f}; }
  int wp = w * 16;
  #pragma unroll
  for (int ks = 0; ks < 2; ks++) {
    int k8 = ks * 4 + fq;
    int rb = wp + fr;
    s16x8 bf = *(const s16x8*)&xT[rb * 64 + ((k8 ^ (rb & 7)) << 3)];
    #pragma unroll
    for (int mi = 0; mi < 4; mi++) {
      int ra = mi * 16 + fr;
      s16x8 af = *(const s16x8*)&Ml[ra * 64 + ((k8 ^ (ra & 7)) << 3)];
      aY[mi] = __builtin_amdgcn_mfma_f32_16x16x32_bf16(af, bf, aY[mi], 0, 0, 0);
    }
  }
  #pragma unroll
  for (int ks = 0; ks < 4; ks++) {
    int k8 = ks * 4 + fq;
    int rb = wp + fr;
    s16x8 bf = *(const s16x8*)&Hs[rb * 128 + ((k8 ^ (rb & 7)) << 3)];
    #pragma unroll
    for (int mi = 0; mi < 4; mi++) {
      int ra = mi * 16 + fr;
      s16x8 af = *(const s16x8*)&Ct[ra * 128 + ((k8 ^ (ra & 7)) << 3)];
      a4[mi] = __builtin_amdgcn_mfma_f32_16x16x32_bf16(af, bf, a4[mi], 0, 0, 0);
    }
  }
  // epilogue: y = Yintra + exp(s_i)*Yinter + D*x   (x read from LDS xT)
  float Dh = Dp[h];
  u16* yrow = yb + ((size_t)b * Ll + tb) * DI + h * 64;
  #pragma unroll
  for (int mi = 0; mi < 4; mi++) {
    int p = wp + fr;
    #pragma unroll
    for (int r = 0; r < 4; r++) {
      int i = mi * 16 + fq * 4 + r;
      float xh = u2f(xT[swz64(p, i)]);
      yrow[(size_t)i * DI + p] = f2bu(aY[mi][r] + pexl[i] * a4[mi][r] + Dh * xh);
    }
  }
}

// ---------------- g = y*silu(z), RMSNorm, *rms_w ----------------
__global__ __launch_bounds__(256) void gate_rms(const u16* __restrict__ y,
    const u16* __restrict__ zbuf, const float* __restrict__ rw, u16* __restrict__ g) {
  int bl = blockIdx.x, tid = threadIdx.x;
  uint4 yv = ((const uint4*)(y + (size_t)bl * DI))[tid];
  uint4 zv = ((const uint4*)(zbuf + (size_t)bl * DI))[tid];
  u32 ya[4] = {yv.x, yv.y, yv.z, yv.w};
  u32 za[4] = {zv.x, zv.y, zv.z, zv.w};
  float gv[8];
  float ss = 0.f;
  #pragma unroll
  for (int jx = 0; jx < 4; jx++) {
    float y0 = blo(ya[jx]), y1 = bhi(ya[jx]);
    float z0 = blo(za[jx]), z1 = bhi(za[jx]);
    float s0 = z0 / (1.f + __expf(-z0));
    float s1 = z1 / (1.f + __expf(-z1));
    gv[jx * 2] = y0 * s0; gv[jx * 2 + 1] = y1 * s1;
    ss += gv[jx * 2] * gv[jx * 2] + gv[jx * 2 + 1] * gv[jx * 2 + 1];
  }
  #pragma unroll
  for (int o = 32; o; o >>= 1) ss += __shfl_down(ss, o);
  __shared__ float red[4];
  int wv = tid >> 6, ln = tid & 63;
  if (ln == 0) red[wv] = ss;
  __syncthreads();
  ss = red[0] + red[1] + red[2] + red[3];
  float scale = rsqrtf(ss * (1.f / DI) + 1e-5f);
  const float* rwp = rw + tid * 8;
  ushort4 o0, o1;
  o0.x = f2bu(gv[0] * scale * rwp[0]); o0.y = f2bu(gv[1] * scale * rwp[1]);
  o0.z = f2bu(gv[2] * scale * rwp[2]); o0.w = f2bu(gv[3] * scale * rwp[3]);
  o1.x = f2bu(gv[4] * scale * rwp[4]); o1.y = f2bu(gv[5] * scale * rwp[5]);
  o1.z = f2bu(gv[6] * scale * rwp[6]); o1.w = f2bu(gv[7] * scale * rwp[7]);
  ushort4* gp = (ushort4*)(g + (size_t)bl * DI + tid * 8);
  gp[0] = o0; gp[1] = o1;
}

extern "C" void kernel_launch(void* const* d_in, const int* in_sizes, int n_in,
                              void* d_out, int out_size, void* d_ws, size_t ws_size,
                              hipStream_t stream) {
  const float* x    = (const float*)d_in[0];
  const float* lnw  = (const float*)d_in[1];
  const float* lnb  = (const float*)d_in[2];
  const float* w1   = (const float*)d_in[3];
  const float* cw   = (const float*)d_in[4];
  const float* cb   = (const float*)d_in[5];
  const float* dtb  = (const float*)d_in[6];
  const float* alog = (const float*)d_in[7];
  const float* Dp   = (const float*)d_in[8];
  const float* rw   = (const float*)d_in[9];
  const float* w2   = (const float*)d_in[10];

  // workspace layout (bytes); overlays are stream-order-safe:
  //   ub/W1b (dead after in_proj) under conv; xbc+dtraw (dead after conv/cumsum)
  //   under Sbuf; state_pass converts Sbuf -> hstart IN PLACE; gb (written by
  //   gate_rms, after chunk_out consumed hstart) overlays Sbuf.
  char* ws = (char*)d_ws;
  u16*   ub     = (u16*)(ws + 0);            // 16,777,216
  u16*   W1b    = (u16*)(ws + 16777216);     // 9,175,040
  u16*   conv   = (u16*)(ws + 0);            // 37,748,736 (overlays ub+W1b)
  u16*   zbuf   = (u16*)(ws + 37748736);     // 33,554,432
  u16*   xbc    = (u16*)(ws + 71303168);     // 37,748,736
  u16*   dtraw  = (u16*)(ws + 109051904);    // 524,288
  u16*   Sbuf   = (u16*)(ws + 71303168);     // 67,108,864 (overlays xbc+dtraw)
  u16*   gb     = (u16*)(ws + 71303168);     // 33,554,432 (overlays Sbuf)
  float* dtv    = (float*)(ws + 138412032);  // 1,048,576
  float* sv     = (float*)(ws + 139460608);  // 1,048,576
  u16*   yb     = (u16*)(ws + 140509184);    // 33,554,432
  u16*   W2b    = (u16*)(ws + 174063616);    // 4,194,304 -> end 178,257,920
  if (ws_size < 178257920u) return;

  float* out = (float*)d_out;

  cvt_pad<<<(NP_PAD * 1024) / 256, 256, 0, stream>>>(w1, W1b, NP_PAD * 1024, 1024, NP);
  cvt_pad<<<(1024 * 2048) / 256, 256, 0, stream>>>(w2, W2b, 1024 * 2048, 2048, 1024);
  ln_kernel<<<BL, 256, 0, stream>>>(x, lnw, lnb, ub);
  gemm_nt<0><<<dim3(64, 35), 256, 0, stream>>>(ub, W1b, zbuf, xbc, dtraw, nullptr, NP, 1024);
  conv_silu<<<(BL * CD) / 256, 256, 0, stream>>>(xbc, cw, cb, conv);
  dt_cumsum<<<1024, 256, 0, stream>>>(dtraw, dtb, alog, dtv, sv);
  chunk_state<<<4096, 256, 0, stream>>>(conv, dtv, sv, Sbuf);
  state_pass<<<1024, 256, 0, stream>>>(Sbuf, sv);
  chunk_out<<<4096, 256, 0, stream>>>(conv, Sbuf, dtv, sv, Dp, yb);
  gate_rms<<<BL, 256, 0, stream>>>(yb, zbuf, rw, gb);
  gemm_nt<1><<<dim3(64, 8), 256, 0, stream>>>(gb, W2b, out, nullptr, nullptr, x, 1024, 2048);
}